// Round 1
// baseline (430.240 us; speedup 1.0000x reference)
//
#include <hip/hip_runtime.h>
#include <stdint.h>
#include <stddef.h>

#define B_ 4
#define T_ 8192
#define D_ 1024
#define NBLK 64
#define SEGL 128
#define TOPK_ 16
#define NS 21          // 16 micro + 4 macro + 1 glob
#define MPAD 96
#define RMS_EPS_ 1.1920929e-07f

typedef float f32x4 __attribute__((ext_vector_type(4)));
typedef __bf16 bf16x8 __attribute__((ext_vector_type(8)));
typedef unsigned short us8 __attribute__((ext_vector_type(8)));

__device__ __forceinline__ unsigned short f2bf(float f) {
    union { float f; unsigned int u; } v; v.f = f;
    unsigned int r = v.u + 0x7FFFu + ((v.u >> 16) & 1u);
    return (unsigned short)(r >> 16);
}
__device__ __forceinline__ float4 ld4(const float* p) { return *(const float4*)p; }

// ---------------------------------------------------------------------------
// K1: per-(b,blk) segment mean (fp32), hid_score = ||mean||, sur_score = mean(nll)
// grid 256 (b*64+blk), block 512. Streams all 128 MB of prev_hidden, coalesced float4.
// ---------------------------------------------------------------------------
__global__ __launch_bounds__(512) void seg_stats(
        const float* __restrict__ ph, const float* __restrict__ nll,
        float* __restrict__ seg_mean, float* __restrict__ hid, float* __restrict__ sur) {
    int g = blockIdx.x; int b = g >> 6; int blk = g & 63;
    int tid = threadIdx.x; int half = tid >> 8; int c = tid & 255;
    const float* base = ph + ((size_t)b * T_ + blk * SEGL + half * 64) * D_ + 4 * c;
    float ax = 0.f, ay = 0.f, az = 0.f, aw = 0.f;
    #pragma unroll 8
    for (int r = 0; r < 64; r++) {
        float4 v = ld4(base + (size_t)r * D_);
        ax += v.x; ay += v.y; az += v.z; aw += v.w;
    }
    __shared__ float4 tmp[256];
    __shared__ float red[256];
    __shared__ float nl[128];
    if (tid < 128) nl[tid] = nll[b * T_ + blk * SEGL + tid];
    if (half) { float4 t; t.x = ax; t.y = ay; t.z = az; t.w = aw; tmp[c] = t; }
    __syncthreads();
    if (!half) {
        float4 t2 = tmp[c];
        float mx = (ax + t2.x) * (1.f/128.f), my = (ay + t2.y) * (1.f/128.f);
        float mz = (az + t2.z) * (1.f/128.f), mw = (aw + t2.w) * (1.f/128.f);
        float4 m; m.x = mx; m.y = my; m.z = mz; m.w = mw;
        *(float4*)(seg_mean + (size_t)g * D_ + 4 * c) = m;
        red[c] = mx*mx + my*my + mz*mz + mw*mw;
    }
    __syncthreads();
    for (int s2 = 128; s2 > 0; s2 >>= 1) { if (tid < s2) red[tid] += red[tid + s2]; __syncthreads(); }
    for (int s2 = 64;  s2 > 0; s2 >>= 1) { if (tid < s2) nl[tid]  += nl[tid + s2];  __syncthreads(); }
    if (tid == 0) { hid[g] = sqrtf(red[0]); sur[g] = nl[0] * (1.f/128.f); }
}

// ---------------------------------------------------------------------------
// K2: zscore(hid)+zscore(sur), top-16 by rank, indices sorted ascending (lane order).
// grid B, block 64 (one wave).
// ---------------------------------------------------------------------------
__global__ __launch_bounds__(64) void score_topk(
        const float* __restrict__ hid, const float* __restrict__ sur, int* __restrict__ idx) {
    int b = blockIdx.x; int l = threadIdx.x;
    float h = hid[b * NBLK + l];
    float s = sur[b * NBLK + l];
    float mh = h; for (int o = 32; o; o >>= 1) mh += __shfl_xor(mh, o); mh *= (1.f/64.f);
    float dh = h - mh; float vh = dh * dh;
    for (int o = 32; o; o >>= 1) vh += __shfl_xor(vh, o); vh *= (1.f/64.f);
    float sh = fmaxf(sqrtf(vh), 1e-6f);
    float ms = s; for (int o = 32; o; o >>= 1) ms += __shfl_xor(ms, o); ms *= (1.f/64.f);
    float ds = s - ms; float vs = ds * ds;
    for (int o = 32; o; o >>= 1) vs += __shfl_xor(vs, o); vs *= (1.f/64.f);
    float ss = fmaxf(sqrtf(vs), 1e-6f);
    float z = dh / sh + ds / ss;
    __shared__ float sc[64];
    sc[l] = z;
    __syncthreads();
    int rank = 0;
    for (int j = 0; j < 64; j++) {
        float oj = sc[j];
        rank += (oj > z) || (oj == z && j < l);
    }
    bool sel = rank < TOPK_;
    unsigned long long mask = __ballot(sel);
    int pos = __popcll(mask & ((1ull << l) - 1ull));
    if (sel) idx[b * TOPK_ + pos] = l;
}

// ---------------------------------------------------------------------------
// K3: assemble feats (MPAD x 2048) in bf16. Row r=b*21+s; rows >=84 zero-padded.
// grid 96, block 256 (thread t owns float4 col 4t of each half).
// ---------------------------------------------------------------------------
__global__ __launch_bounds__(256) void feats_build(
        const float* __restrict__ ph, const float* __restrict__ seg_mean,
        const int* __restrict__ idx, unsigned short* __restrict__ feats) {
    int r = blockIdx.x; int t = threadIdx.x;
    unsigned short* row0 = feats + (size_t)r * 2048 + 4 * t;          // mean half
    unsigned short* row1 = row0 + 1024;                                // last half
    if (r >= B_ * NS) {
        ushort4 z; z.x = z.y = z.z = z.w = 0;
        *(ushort4*)row0 = z; *(ushort4*)row1 = z;
        return;
    }
    int b = r / NS, s = r % NS;
    float mx = 0, my = 0, mz = 0, mw = 0;
    int lastrow;
    if (s < 16) {
        int blk = idx[b * TOPK_ + s];
        float4 v = ld4(seg_mean + (size_t)(b * NBLK + blk) * D_ + 4 * t);
        mx = v.x; my = v.y; mz = v.z; mw = v.w;
        lastrow = blk * SEGL + SEGL - 1;
    } else if (s < 20) {
        int m = s - 16;
        for (int j = 0; j < 16; j++) {
            float4 v = ld4(seg_mean + (size_t)(b * NBLK + m * 16 + j) * D_ + 4 * t);
            mx += v.x; my += v.y; mz += v.z; mw += v.w;
        }
        mx *= (1.f/16.f); my *= (1.f/16.f); mz *= (1.f/16.f); mw *= (1.f/16.f);
        lastrow = m * 2048 + 2047;
    } else {
        for (int j = 0; j < 64; j++) {
            float4 v = ld4(seg_mean + (size_t)(b * NBLK + j) * D_ + 4 * t);
            mx += v.x; my += v.y; mz += v.z; mw += v.w;
        }
        mx *= (1.f/64.f); my *= (1.f/64.f); mz *= (1.f/64.f); mw *= (1.f/64.f);
        lastrow = T_ - 1;
    }
    float4 lv = ld4(ph + ((size_t)b * T_ + lastrow) * D_ + 4 * t);
    ushort4 hm; hm.x = f2bf(mx); hm.y = f2bf(my); hm.z = f2bf(mz); hm.w = f2bf(mw);
    ushort4 hl; hl.x = f2bf(lv.x); hl.y = f2bf(lv.y); hl.z = f2bf(lv.z); hl.w = f2bf(lv.w);
    *(ushort4*)row0 = hm;
    *(ushort4*)row1 = hl;
}

// ---------------------------------------------------------------------------
// K4: bf16 MFMA GEMM  C[MPAD x 1024] = A[MPAD x K](bf16) @ Bw[1024 x K](fp32)^T
// Weights converted fp32->bf16 during LDS staging (read exactly once in fp32).
// grid (16 n-tiles, 2 m-halves of 48), block 256. Writes both fp32 and bf16 C.
// ---------------------------------------------------------------------------
template<int K>
__global__ __launch_bounds__(256) void gemm_bt(
        const unsigned short* __restrict__ A, const float* __restrict__ Bw,
        float* __restrict__ Cf, unsigned short* __restrict__ Cb) {
    constexpr int NT = 64, KT = 128;
    __shared__ unsigned short Bs[NT][KT + 8];   // stride 136 (272 B, 16B-aligned rows)
    int n0 = blockIdx.x * NT;
    int m0 = blockIdx.y * 48;
    int tid = threadIdx.x;
    int wave = tid >> 6, lane = tid & 63;
    int quad = lane >> 4, l16 = lane & 15;
    f32x4 acc[3];
    #pragma unroll
    for (int i = 0; i < 3; i++) acc[i] = (f32x4){0.f, 0.f, 0.f, 0.f};
    int srow = tid >> 2, scol = tid & 3;
    const float* bptr = Bw + (size_t)(n0 + srow) * K;
    for (int k0 = 0; k0 < K; k0 += KT) {
        #pragma unroll
        for (int i = 0; i < 8; i++) {
            int c = scol + 4 * i;
            float4 v = ld4(bptr + k0 + 4 * c);
            ushort4 h; h.x = f2bf(v.x); h.y = f2bf(v.y); h.z = f2bf(v.z); h.w = f2bf(v.w);
            *(ushort4*)&Bs[srow][4 * c] = h;
        }
        __syncthreads();
        #pragma unroll
        for (int kk = 0; kk < KT; kk += 32) {
            us8 braw = *(const us8*)&Bs[wave * 16 + l16][kk + quad * 8];
            bf16x8 bf = __builtin_bit_cast(bf16x8, braw);
            #pragma unroll
            for (int mi = 0; mi < 3; mi++) {
                us8 araw = *(const us8*)(A + (size_t)(m0 + mi * 16 + l16) * K + k0 + kk + quad * 8);
                bf16x8 af = __builtin_bit_cast(bf16x8, araw);
                acc[mi] = __builtin_amdgcn_mfma_f32_16x16x32_bf16(af, bf, acc[mi], 0, 0, 0);
            }
        }
        __syncthreads();
    }
    int col = n0 + wave * 16 + l16;
    #pragma unroll
    for (int mi = 0; mi < 3; mi++) {
        #pragma unroll
        for (int r = 0; r < 4; r++) {
            int row = m0 + mi * 16 + quad * 4 + r;
            float v = acc[mi][r];
            Cf[(size_t)row * 1024 + col] = v;
            Cb[(size_t)row * 1024 + col] = f2bf(v);
        }
    }
}

// ---------------------------------------------------------------------------
// K5: row-wise RMSNorm of pre-summaries (fp32 in) -> summaries (bf16 out). grid 96.
// ---------------------------------------------------------------------------
__global__ __launch_bounds__(256) void rmsnorm_rows(
        const float* __restrict__ x, unsigned short* __restrict__ y) {
    int r = blockIdx.x; int t = threadIdx.x;
    float4 v = ld4(x + (size_t)r * D_ + 4 * t);
    __shared__ float red[256];
    red[t] = v.x*v.x + v.y*v.y + v.z*v.z + v.w*v.w;
    __syncthreads();
    for (int s2 = 128; s2 > 0; s2 >>= 1) { if (t < s2) red[t] += red[t + s2]; __syncthreads(); }
    float scale = rsqrtf(red[0] * (1.f/1024.f) + RMS_EPS_);
    ushort4 h;
    h.x = f2bf(v.x * scale); h.y = f2bf(v.y * scale);
    h.z = f2bf(v.z * scale); h.w = f2bf(v.w * scale);
    *(ushort4*)(y + (size_t)r * D_ + 4 * t) = h;
}

// ---------------------------------------------------------------------------
// K6: per-(b,q) logits (query . keys)/32, softmax over 21, out = attn @ valsO.
// grid 256 (b*64+q), block 256 (4 waves).
// ---------------------------------------------------------------------------
__global__ __launch_bounds__(256) void attn_out(
        const float* __restrict__ query, const float* __restrict__ keys,
        const float* __restrict__ valsO, float* __restrict__ out) {
    int g = blockIdx.x; int b = g >> 6; int q = g & 63;
    int tid = threadIdx.x, wave = tid >> 6, lane = tid & 63;
    __shared__ float attnw[24];
    const float* qrow = query + (size_t)q * D_ + lane * 16;
    float4 qv0 = ld4(qrow), qv1 = ld4(qrow + 4), qv2 = ld4(qrow + 8), qv3 = ld4(qrow + 12);
    for (int s = wave; s < NS; s += 4) {
        const float* krow = keys + (size_t)(b * NS + s) * D_ + lane * 16;
        float4 k0 = ld4(krow), k1 = ld4(krow + 4), k2 = ld4(krow + 8), k3 = ld4(krow + 12);
        float a = qv0.x*k0.x + qv0.y*k0.y + qv0.z*k0.z + qv0.w*k0.w
                + qv1.x*k1.x + qv1.y*k1.y + qv1.z*k1.z + qv1.w*k1.w
                + qv2.x*k2.x + qv2.y*k2.y + qv2.z*k2.z + qv2.w*k2.w
                + qv3.x*k3.x + qv3.y*k3.y + qv3.z*k3.z + qv3.w*k3.w;
        for (int o = 32; o; o >>= 1) a += __shfl_xor(a, o);
        if (lane == 0) attnw[s] = a * 0.03125f;   // /sqrt(1024)
    }
    __syncthreads();
    if (tid == 0) {
        float mx = -1e30f;
        for (int s = 0; s < NS; s++) mx = fmaxf(mx, attnw[s]);
        float sum = 0.f;
        for (int s = 0; s < NS; s++) { float e = expf(attnw[s] - mx); attnw[s] = e; sum += e; }
        float inv = 1.f / sum;
        for (int s = 0; s < NS; s++) attnw[s] *= inv;
    }
    __syncthreads();
    float ax = 0, ay = 0, az = 0, aw = 0;
    #pragma unroll
    for (int s = 0; s < NS; s++) {
        float w = attnw[s];
        float4 v = ld4(valsO + (size_t)(b * NS + s) * D_ + 4 * tid);
        ax += w * v.x; ay += w * v.y; az += w * v.z; aw += w * v.w;
    }
    float4 o4; o4.x = ax; o4.y = ay; o4.z = az; o4.w = aw;
    *(float4*)(out + (size_t)g * D_ + 4 * tid) = o4;
}

// ---------------------------------------------------------------------------
extern "C" void kernel_launch(void* const* d_in, const int* in_sizes, int n_in,
                              void* d_out, int out_size, void* d_ws, size_t ws_size,
                              hipStream_t stream) {
    (void)in_sizes; (void)n_in; (void)out_size; (void)ws_size;
    const float* ph    = (const float*)d_in[0];
    const float* nll   = (const float*)d_in[1];
    const float* query = (const float*)d_in[2];
    const float* W_sum = (const float*)d_in[3];
    const float* W_k   = (const float*)d_in[4];
    const float* W_v   = (const float*)d_in[5];
    const float* W_o   = (const float*)d_in[6];
    float* out = (float*)d_out;

    char* ws = (char*)d_ws;
    // byte offsets (16B aligned)
    float*          seg_mean = (float*)(ws + 0);                 // 4*64*1024 f32   = 1048576 B
    float*          hid      = (float*)(ws + 1048576);           // 256 f32
    float*          sur      = (float*)(ws + 1049600);           // 256 f32
    int*            idx      = (int*)  (ws + 1050624);           // 64 int
    unsigned short* feats    = (unsigned short*)(ws + 1050880);  // 96*2048 bf16    = 393216 B
    float*          presum_f = (float*)(ws + 1444096);           // 96*1024 f32     = 393216 B
    unsigned short* presum_b = (unsigned short*)(ws + 1837312);  // 196608 B (unused)
    unsigned short* summ_b   = (unsigned short*)(ws + 2033920);  // 196608 B
    float*          keys_f   = (float*)(ws + 2230528);           // 393216 B
    unsigned short* keys_b   = (unsigned short*)(ws + 2623744);  // 196608 B (unused)
    float*          vals_f   = (float*)(ws + 2820352);           // 393216 B (unused)
    unsigned short* vals_b   = (unsigned short*)(ws + 3213568);  // 196608 B
    float*          valsO_f  = (float*)(ws + 3410176);           // 393216 B
    unsigned short* valsO_b  = (unsigned short*)(ws + 3803392);  // 196608 B (unused)

    seg_stats<<<B_ * NBLK, 512, 0, stream>>>(ph, nll, seg_mean, hid, sur);
    score_topk<<<B_, 64, 0, stream>>>(hid, sur, idx);
    feats_build<<<MPAD, 256, 0, stream>>>(ph, seg_mean, idx, feats);
    gemm_bt<2048><<<dim3(16, 2), 256, 0, stream>>>(feats, W_sum, presum_f, presum_b);
    rmsnorm_rows<<<MPAD, 256, 0, stream>>>(presum_f, summ_b);
    gemm_bt<1024><<<dim3(16, 2), 256, 0, stream>>>(summ_b, W_k, keys_f, keys_b);
    gemm_bt<1024><<<dim3(16, 2), 256, 0, stream>>>(summ_b, W_v, vals_f, vals_b);
    gemm_bt<1024><<<dim3(16, 2), 256, 0, stream>>>(vals_b, W_o, valsO_f, valsO_b);
    attn_out<<<B_ * NBLK, 256, 0, stream>>>(query, keys_f, valsO_f, out);
}

// Round 2
// 261.458 us; speedup vs baseline: 1.6455x; 1.6455x over previous
//
#include <hip/hip_runtime.h>
#include <stdint.h>
#include <stddef.h>

#define B_ 4
#define T_ 8192
#define D_ 1024
#define NBLK 64
#define SEGL 128
#define TOPK_ 16
#define NS 21          // 16 micro + 4 macro + 1 glob
#define MPAD 96
#define RMS_EPS_ 1.1920929e-07f

typedef float f32x4 __attribute__((ext_vector_type(4)));
typedef __bf16 bf16x8 __attribute__((ext_vector_type(8)));
typedef unsigned short us8 __attribute__((ext_vector_type(8)));

__device__ __forceinline__ unsigned short f2bf(float f) {
    union { float f; unsigned int u; } v; v.f = f;
    unsigned int r = v.u + 0x7FFFu + ((v.u >> 16) & 1u);
    return (unsigned short)(r >> 16);
}
__device__ __forceinline__ float4 ld4(const float* p) { return *(const float4*)p; }

// ---------------------------------------------------------------------------
// K1: per-(b,blk) segment mean (fp32), hid_score = ||mean||, sur_score = mean(nll)
// grid 256 (b*64+blk), block 512. Streams all 128 MB of prev_hidden, coalesced float4.
// ---------------------------------------------------------------------------
__global__ __launch_bounds__(512) void seg_stats(
        const float* __restrict__ ph, const float* __restrict__ nll,
        float* __restrict__ seg_mean, float* __restrict__ hid, float* __restrict__ sur) {
    int g = blockIdx.x; int b = g >> 6; int blk = g & 63;
    int tid = threadIdx.x; int half = tid >> 8; int c = tid & 255;
    const float* base = ph + ((size_t)b * T_ + blk * SEGL + half * 64) * D_ + 4 * c;
    float ax = 0.f, ay = 0.f, az = 0.f, aw = 0.f;
    #pragma unroll 8
    for (int r = 0; r < 64; r++) {
        float4 v = ld4(base + (size_t)r * D_);
        ax += v.x; ay += v.y; az += v.z; aw += v.w;
    }
    __shared__ float4 tmp[256];
    __shared__ float red[256];
    __shared__ float nl[128];
    if (tid < 128) nl[tid] = nll[b * T_ + blk * SEGL + tid];
    if (half) { float4 t; t.x = ax; t.y = ay; t.z = az; t.w = aw; tmp[c] = t; }
    __syncthreads();
    if (!half) {
        float4 t2 = tmp[c];
        float mx = (ax + t2.x) * (1.f/128.f), my = (ay + t2.y) * (1.f/128.f);
        float mz = (az + t2.z) * (1.f/128.f), mw = (aw + t2.w) * (1.f/128.f);
        float4 m; m.x = mx; m.y = my; m.z = mz; m.w = mw;
        *(float4*)(seg_mean + (size_t)g * D_ + 4 * c) = m;
        red[c] = mx*mx + my*my + mz*mz + mw*mw;
    }
    __syncthreads();
    for (int s2 = 128; s2 > 0; s2 >>= 1) { if (tid < s2) red[tid] += red[tid + s2]; __syncthreads(); }
    for (int s2 = 64;  s2 > 0; s2 >>= 1) { if (tid < s2) nl[tid]  += nl[tid + s2];  __syncthreads(); }
    if (tid == 0) { hid[g] = sqrtf(red[0]); sur[g] = nl[0] * (1.f/128.f); }
}

// ---------------------------------------------------------------------------
// K2: zscore(hid)+zscore(sur), top-16 by rank, indices sorted ascending (lane order).
// grid B, block 64 (one wave).
// ---------------------------------------------------------------------------
__global__ __launch_bounds__(64) void score_topk(
        const float* __restrict__ hid, const float* __restrict__ sur, int* __restrict__ idx) {
    int b = blockIdx.x; int l = threadIdx.x;
    float h = hid[b * NBLK + l];
    float s = sur[b * NBLK + l];
    float mh = h; for (int o = 32; o; o >>= 1) mh += __shfl_xor(mh, o); mh *= (1.f/64.f);
    float dh = h - mh; float vh = dh * dh;
    for (int o = 32; o; o >>= 1) vh += __shfl_xor(vh, o); vh *= (1.f/64.f);
    float sh = fmaxf(sqrtf(vh), 1e-6f);
    float ms = s; for (int o = 32; o; o >>= 1) ms += __shfl_xor(ms, o); ms *= (1.f/64.f);
    float ds = s - ms; float vs = ds * ds;
    for (int o = 32; o; o >>= 1) vs += __shfl_xor(vs, o); vs *= (1.f/64.f);
    float ss = fmaxf(sqrtf(vs), 1e-6f);
    float z = dh / sh + ds / ss;
    __shared__ float sc[64];
    sc[l] = z;
    __syncthreads();
    int rank = 0;
    for (int j = 0; j < 64; j++) {
        float oj = sc[j];
        rank += (oj > z) || (oj == z && j < l);
    }
    bool sel = rank < TOPK_;
    unsigned long long mask = __ballot(sel);
    int pos = __popcll(mask & ((1ull << l) - 1ull));
    if (sel) idx[b * TOPK_ + pos] = l;
}

// ---------------------------------------------------------------------------
// K3: assemble feats (MPAD x 2048) in bf16. Row r=b*21+s; rows >=84 zero-padded.
// ---------------------------------------------------------------------------
__global__ __launch_bounds__(256) void feats_build(
        const float* __restrict__ ph, const float* __restrict__ seg_mean,
        const int* __restrict__ idx, unsigned short* __restrict__ feats) {
    int r = blockIdx.x; int t = threadIdx.x;
    unsigned short* row0 = feats + (size_t)r * 2048 + 4 * t;          // mean half
    unsigned short* row1 = row0 + 1024;                                // last half
    if (r >= B_ * NS) {
        ushort4 z; z.x = z.y = z.z = z.w = 0;
        *(ushort4*)row0 = z; *(ushort4*)row1 = z;
        return;
    }
    int b = r / NS, s = r % NS;
    float mx = 0, my = 0, mz = 0, mw = 0;
    int lastrow;
    if (s < 16) {
        int blk = idx[b * TOPK_ + s];
        float4 v = ld4(seg_mean + (size_t)(b * NBLK + blk) * D_ + 4 * t);
        mx = v.x; my = v.y; mz = v.z; mw = v.w;
        lastrow = blk * SEGL + SEGL - 1;
    } else if (s < 20) {
        int m = s - 16;
        for (int j = 0; j < 16; j++) {
            float4 v = ld4(seg_mean + (size_t)(b * NBLK + m * 16 + j) * D_ + 4 * t);
            mx += v.x; my += v.y; mz += v.z; mw += v.w;
        }
        mx *= (1.f/16.f); my *= (1.f/16.f); mz *= (1.f/16.f); mw *= (1.f/16.f);
        lastrow = m * 2048 + 2047;
    } else {
        for (int j = 0; j < 64; j++) {
            float4 v = ld4(seg_mean + (size_t)(b * NBLK + j) * D_ + 4 * t);
            mx += v.x; my += v.y; mz += v.z; mw += v.w;
        }
        mx *= (1.f/64.f); my *= (1.f/64.f); mz *= (1.f/64.f); mw *= (1.f/64.f);
        lastrow = T_ - 1;
    }
    float4 lv = ld4(ph + ((size_t)b * T_ + lastrow) * D_ + 4 * t);
    ushort4 hm; hm.x = f2bf(mx); hm.y = f2bf(my); hm.z = f2bf(mz); hm.w = f2bf(mw);
    ushort4 hl; hl.x = f2bf(lv.x); hl.y = f2bf(lv.y); hl.z = f2bf(lv.z); hl.w = f2bf(lv.w);
    *(ushort4*)row0 = hm;
    *(ushort4*)row1 = hl;
}

// ---------------------------------------------------------------------------
// K4 (v2): bf16 MFMA GEMM  C[96x1024] = A[96xK](bf16) @ Bw[1024xK](fp32)^T
// No LDS staging, no K-loop barriers. B-fragments loaded straight from fp32
// weights into registers (lane l16 -> row n0+l16, contiguous 32 B), converted
// to bf16 in-register. grid (64 n-strips, 2 m-halves) x 4 waves split-K 4-way
// -> 512 independent waves, unroll-4 keeps ~5 KB/wave of loads in flight.
// Split-K reduced via 12 KB LDS at the end.
// ---------------------------------------------------------------------------
template<int K>
__global__ __launch_bounds__(256) void gemm_bt2(
        const unsigned short* __restrict__ A, const float* __restrict__ Bw,
        float* __restrict__ Cf, unsigned short* __restrict__ Cb) {
    constexpr int KW = K / 4;        // per-wave K chunk
    constexpr int NSTEP = KW / 32;   // 16 (K=2048) or 8 (K=1024)
    int n0 = blockIdx.x * 16;
    int m0 = blockIdx.y * 48;
    int tid = threadIdx.x, wave = tid >> 6, lane = tid & 63;
    int quad = lane >> 4, l16 = lane & 15;
    int kbase = wave * KW;

    f32x4 acc[3];
    #pragma unroll
    for (int i = 0; i < 3; i++) acc[i] = (f32x4){0.f, 0.f, 0.f, 0.f};

    const float* bp = Bw + (size_t)(n0 + l16) * K + kbase + quad * 8;
    const unsigned short* ap = A + (size_t)(m0 + l16) * K + kbase + quad * 8;

    #pragma unroll 4
    for (int s = 0; s < NSTEP; s++) {
        float4 b0 = ld4(bp + s * 32);
        float4 b1 = ld4(bp + s * 32 + 4);
        us8 braw;
        braw[0] = f2bf(b0.x); braw[1] = f2bf(b0.y); braw[2] = f2bf(b0.z); braw[3] = f2bf(b0.w);
        braw[4] = f2bf(b1.x); braw[5] = f2bf(b1.y); braw[6] = f2bf(b1.z); braw[7] = f2bf(b1.w);
        bf16x8 bf = __builtin_bit_cast(bf16x8, braw);
        #pragma unroll
        for (int mi = 0; mi < 3; mi++) {
            us8 araw = *(const us8*)(ap + (size_t)mi * 16 * K + s * 32);
            bf16x8 af = __builtin_bit_cast(bf16x8, araw);
            acc[mi] = __builtin_amdgcn_mfma_f32_16x16x32_bf16(af, bf, acc[mi], 0, 0, 0);
        }
    }

    // split-K reduction across the 4 waves
    __shared__ float part[4][3][16][16];   // 12 KB
    #pragma unroll
    for (int mi = 0; mi < 3; mi++)
        #pragma unroll
        for (int r = 0; r < 4; r++)
            part[wave][mi][quad * 4 + r][l16] = acc[mi][r];
    __syncthreads();
    for (int o = tid; o < 768; o += 256) {
        int mi = o >> 8; int rr = (o >> 4) & 15; int cc = o & 15;
        float v = part[0][mi][rr][cc] + part[1][mi][rr][cc]
                + part[2][mi][rr][cc] + part[3][mi][rr][cc];
        int row = m0 + mi * 16 + rr; int col = n0 + cc;
        Cf[(size_t)row * 1024 + col] = v;
        Cb[(size_t)row * 1024 + col] = f2bf(v);
    }
}

// ---------------------------------------------------------------------------
// K5: row-wise RMSNorm of pre-summaries (fp32 in) -> summaries (bf16 out). grid 96.
// ---------------------------------------------------------------------------
__global__ __launch_bounds__(256) void rmsnorm_rows(
        const float* __restrict__ x, unsigned short* __restrict__ y) {
    int r = blockIdx.x; int t = threadIdx.x;
    float4 v = ld4(x + (size_t)r * D_ + 4 * t);
    __shared__ float red[256];
    red[t] = v.x*v.x + v.y*v.y + v.z*v.z + v.w*v.w;
    __syncthreads();
    for (int s2 = 128; s2 > 0; s2 >>= 1) { if (t < s2) red[t] += red[t + s2]; __syncthreads(); }
    float scale = rsqrtf(red[0] * (1.f/1024.f) + RMS_EPS_);
    ushort4 h;
    h.x = f2bf(v.x * scale); h.y = f2bf(v.y * scale);
    h.z = f2bf(v.z * scale); h.w = f2bf(v.w * scale);
    *(ushort4*)(y + (size_t)r * D_ + 4 * t) = h;
}

// ---------------------------------------------------------------------------
// K6: per-(b,q) logits (query . keys)/32, softmax over 21, out = attn @ valsO.
// grid 256 (b*64+q), block 256 (4 waves).
// ---------------------------------------------------------------------------
__global__ __launch_bounds__(256) void attn_out(
        const float* __restrict__ query, const float* __restrict__ keys,
        const float* __restrict__ valsO, float* __restrict__ out) {
    int g = blockIdx.x; int b = g >> 6; int q = g & 63;
    int tid = threadIdx.x, wave = tid >> 6, lane = tid & 63;
    __shared__ float attnw[24];
    const float* qrow = query + (size_t)q * D_ + lane * 16;
    float4 qv0 = ld4(qrow), qv1 = ld4(qrow + 4), qv2 = ld4(qrow + 8), qv3 = ld4(qrow + 12);
    for (int s = wave; s < NS; s += 4) {
        const float* krow = keys + (size_t)(b * NS + s) * D_ + lane * 16;
        float4 k0 = ld4(krow), k1 = ld4(krow + 4), k2 = ld4(krow + 8), k3 = ld4(krow + 12);
        float a = qv0.x*k0.x + qv0.y*k0.y + qv0.z*k0.z + qv0.w*k0.w
                + qv1.x*k1.x + qv1.y*k1.y + qv1.z*k1.z + qv1.w*k1.w
                + qv2.x*k2.x + qv2.y*k2.y + qv2.z*k2.z + qv2.w*k2.w
                + qv3.x*k3.x + qv3.y*k3.y + qv3.z*k3.z + qv3.w*k3.w;
        for (int o = 32; o; o >>= 1) a += __shfl_xor(a, o);
        if (lane == 0) attnw[s] = a * 0.03125f;   // /sqrt(1024)
    }
    __syncthreads();
    if (tid == 0) {
        float mx = -1e30f;
        for (int s = 0; s < NS; s++) mx = fmaxf(mx, attnw[s]);
        float sum = 0.f;
        for (int s = 0; s < NS; s++) { float e = expf(attnw[s] - mx); attnw[s] = e; sum += e; }
        float inv = 1.f / sum;
        for (int s = 0; s < NS; s++) attnw[s] *= inv;
    }
    __syncthreads();
    float ax = 0, ay = 0, az = 0, aw = 0;
    #pragma unroll
    for (int s = 0; s < NS; s++) {
        float w = attnw[s];
        float4 v = ld4(valsO + (size_t)(b * NS + s) * D_ + 4 * tid);
        ax += w * v.x; ay += w * v.y; az += w * v.z; aw += w * v.w;
    }
    float4 o4; o4.x = ax; o4.y = ay; o4.z = az; o4.w = aw;
    *(float4*)(out + (size_t)g * D_ + 4 * tid) = o4;
}

// ---------------------------------------------------------------------------
extern "C" void kernel_launch(void* const* d_in, const int* in_sizes, int n_in,
                              void* d_out, int out_size, void* d_ws, size_t ws_size,
                              hipStream_t stream) {
    (void)in_sizes; (void)n_in; (void)out_size; (void)ws_size;
    const float* ph    = (const float*)d_in[0];
    const float* nll   = (const float*)d_in[1];
    const float* query = (const float*)d_in[2];
    const float* W_sum = (const float*)d_in[3];
    const float* W_k   = (const float*)d_in[4];
    const float* W_v   = (const float*)d_in[5];
    const float* W_o   = (const float*)d_in[6];
    float* out = (float*)d_out;

    char* ws = (char*)d_ws;
    float*          seg_mean = (float*)(ws + 0);                 // 4*64*1024 f32   = 1048576 B
    float*          hid      = (float*)(ws + 1048576);           // 256 f32
    float*          sur      = (float*)(ws + 1049600);           // 256 f32
    int*            idx      = (int*)  (ws + 1050624);           // 64 int
    unsigned short* feats    = (unsigned short*)(ws + 1050880);  // 96*2048 bf16    = 393216 B
    float*          presum_f = (float*)(ws + 1444096);           // 96*1024 f32     = 393216 B
    unsigned short* presum_b = (unsigned short*)(ws + 1837312);  // 196608 B (unused)
    unsigned short* summ_b   = (unsigned short*)(ws + 2033920);  // 196608 B
    float*          keys_f   = (float*)(ws + 2230528);           // 393216 B
    unsigned short* keys_b   = (unsigned short*)(ws + 2623744);  // 196608 B (unused)
    float*          vals_f   = (float*)(ws + 2820352);           // 393216 B (unused)
    unsigned short* vals_b   = (unsigned short*)(ws + 3213568);  // 196608 B
    float*          valsO_f  = (float*)(ws + 3410176);           // 393216 B
    unsigned short* valsO_b  = (unsigned short*)(ws + 3803392);  // 196608 B (unused)

    seg_stats<<<B_ * NBLK, 512, 0, stream>>>(ph, nll, seg_mean, hid, sur);
    score_topk<<<B_, 64, 0, stream>>>(hid, sur, idx);
    feats_build<<<MPAD, 256, 0, stream>>>(ph, seg_mean, idx, feats);
    gemm_bt2<2048><<<dim3(64, 2), 256, 0, stream>>>(feats, W_sum, presum_f, presum_b);
    rmsnorm_rows<<<MPAD, 256, 0, stream>>>(presum_f, summ_b);
    gemm_bt2<1024><<<dim3(64, 2), 256, 0, stream>>>(summ_b, W_k, keys_f, keys_b);
    gemm_bt2<1024><<<dim3(64, 2), 256, 0, stream>>>(summ_b, W_v, vals_f, vals_b);
    gemm_bt2<1024><<<dim3(64, 2), 256, 0, stream>>>(vals_b, W_o, valsO_f, valsO_b);
    attn_out<<<B_ * NBLK, 256, 0, stream>>>(query, keys_f, valsO_f, out);
}